// Round 7
// baseline (226.489 us; speedup 1.0000x reference)
//
#include <hip/hip_runtime.h>
#include <math.h>

#define SPB 3136      // spatial positions per batch (56*56)
#define NB 8
#define MTOT (NB*SPB) // 25088 = 392*64, flattened M across batch
#define EPS 1e-5f

typedef unsigned short u16;
typedef __attribute__((ext_vector_type(8))) short short8;
typedef __attribute__((ext_vector_type(4))) float float4v;

__device__ __forceinline__ float b2f(u16 v){ unsigned u=((unsigned)v)<<16; float f; __builtin_memcpy(&f,&u,4); return f; }
__device__ __forceinline__ u16 f2b(float f){ unsigned u; __builtin_memcpy(&u,&f,4); u += 0x7fffu + ((u>>16)&1u); return (u16)(u>>16); }
__device__ __forceinline__ float gelu_f(float z){ return 0.5f*z*(1.0f+erff(z*0.70710678118654752f)); }

// ---- fused: fold BN constants (block 0) + cast all weights to bf16 (row-major [o][k]) ----
// cst layout: s1[256] t1[256] sg[512] tg[512] s2[256] t2[256]
__global__ void prep_k(const float* b1,const float* g1,const float* be1,const float* m1,const float* v1,
                       const float* bg,const float* gg,const float* beg,const float* mg,const float* vg,
                       const float* b2,const float* g2,const float* be2,const float* m2,const float* v2,
                       const float* __restrict__ w1,const float* __restrict__ wg,const float* __restrict__ w2,
                       u16* __restrict__ w1b,u16* __restrict__ wgb,u16* __restrict__ w2b,
                       float* cst){
  int i = blockIdx.x*512 + threadIdx.x;
  if (blockIdx.x == 0) {
    int t = threadIdx.x;
    if (t < 256) {
      float s = g1[t]*rsqrtf(v1[t]+EPS);
      cst[t] = s; cst[256+t] = b1[t]*s + be1[t] - m1[t]*s;
      float s2 = g2[t]*rsqrtf(v2[t]+EPS);
      cst[1536+t] = s2; cst[1792+t] = b2[t]*s2 + be2[t] - m2[t]*s2;
    }
    float s = gg[t]*rsqrtf(vg[t]+EPS);
    cst[512+t] = s; cst[1024+t] = bg[t]*s + beg[t] - mg[t]*s;
  }
  if (i < 65536)  w1b[i] = f2b(w1[i]);
  if (i < 131072) w2b[i] = f2b(w2[i]);
  if (i < 262144) wgb[i] = f2b(wg[i]);
}

// x [b][c][s] fp32 -> xt [b][s][c] bf16
__global__ void transpose_x_k(const float* __restrict__ x, u16* __restrict__ xt){
  __shared__ float t[32][33];
  int b = blockIdx.z, ct = blockIdx.y, st = blockIdx.x;
  int ts = threadIdx.x, tc = threadIdx.y;
  #pragma unroll
  for (int i=0;i<4;i++){
    int c = tc + i*8;
    t[c][ts] = x[((size_t)(b*256 + ct*32 + c))*SPB + st*32 + ts];
  }
  __syncthreads();
  #pragma unroll
  for (int i=0;i<4;i++){
    int r = tc + i*8;
    xt[((size_t)(b*SPB + st*32 + r))*256 + ct*32 + ts] = f2b(t[ts][r]);
  }
}

// fused row/col parity-min over h = catt [m][256] bf16; outputs bf16 (exact: min of bf16 set)
// rmin[(b*2+xpar)*56 + y][c] = min over x of that parity; cmin[(b*2+ypar)*56 + x][c] = min over y.
__global__ void minrc_k(const u16* __restrict__ catt, u16* __restrict__ rmin, u16* __restrict__ cmin){
  int b = blockIdx.x/56, j = blockIdx.x%56, c = threadIdx.x;
  float mE=3.4e38f, mO=3.4e38f;
  if (blockIdx.y == 0) {          // fixed y=j, min over x
    const u16* base = catt + ((size_t)(b*SPB + j*56))*256 + c;
    #pragma unroll 4
    for (int x=0;x<56;x+=2){
      mE = fminf(mE, b2f(base[(size_t)x*256]));
      mO = fminf(mO, b2f(base[(size_t)(x+1)*256]));
    }
    rmin[((size_t)(b*2+0)*56 + j)*256 + c]=f2b(mE);
    rmin[((size_t)(b*2+1)*56 + j)*256 + c]=f2b(mO);
  } else {                        // fixed x=j, min over y
    const u16* base = catt + ((size_t)(b*SPB + j))*256 + c;
    #pragma unroll 4
    for (int y=0;y<56;y+=2){
      mE = fminf(mE, b2f(base[(size_t)(y*56)*256]));
      mO = fminf(mO, b2f(base[(size_t)((y+1)*56)*256]));
    }
    cmin[((size_t)(b*2+0)*56 + j)*256 + c]=f2b(mE);
    cmin[((size_t)(b*2+1)*56 + j)*256 + c]=f2b(mO);
  }
}

// GEMM: D[m][o] = sum_k A[m][k] * Wt[o][k]; M flattened over batch.
// R1-proven skeleton: BM=64 x BN=128 x BK=32, 4 waves (2x2), wave tile 32x64
// (2x4 MFMA), single 12KB LDS buffer, VGPR-staged loads, 2 barriers/iter,
// fully unrolled K. NEW: fragment-contiguous LDS (chunk c -> offset c*16 = frag
// c>>6, lane c&63) -> conflict-free b128 writes AND reads.
// XJF (GEMM2 only): A is virtually [h | xj(h)]; iterations with k>=256 compute
// xj = max(0, h - min(cmin,rmin)) during staging (compile-time unrolled branch).
// EPI 1: bf16( acc*s + t )              -> out [m][256] at col o0 (h-only catt)
// EPI 2: bf16( gelu(acc*s + t) )        -> out [m][512] at col o0
// EPI 3: fp32( acc*s + t + x[b][o][s] ) -> out [b][256][s]
template<int KTOT, int AST, int EPI, bool XJF>
__global__ __launch_bounds__(256) void gemm_k(
    const u16* __restrict__ Ain, const u16* __restrict__ Wt,
    const float* __restrict__ scale, const float* __restrict__ bias,
    void* __restrict__ outp, const float* __restrict__ resid,
    const u16* __restrict__ cminb, const u16* __restrict__ rminb)
{
  __shared__ __align__(16) u16 smem[EPI==3 ? 8704 : 8192]; // staging uses 6144 u16 (12KB)
  const int tid = threadIdx.x;
  const int m0 = blockIdx.x * 64;
  const int o0 = blockIdx.y * 128;
  const int lane = tid & 63, wid = tid >> 6;
  const int quad = lane >> 4, l16 = lane & 15;
  const int wm = wid & 1, wn = wid >> 1;
  constexpr int NIT = KTOT/32;

  float4v acc[2][4];
  #pragma unroll
  for (int i=0;i<2;i++)
    #pragma unroll
    for (int j=0;j<4;j++) acc[i][j] = (float4v){0.f,0.f,0.f,0.f};

  // staging chunk t: A row = ((t>>6)<<4)+(t&15), k-off = ((t>>4)&3)*8
  const int rowA = ((tid>>6)<<4) + (tid&15);
  const int koff = ((tid>>4)&3)*8;
  const u16* aG  = Ain + (size_t)(m0+rowA)*AST + koff;
  const u16* bG0 = Wt  + (size_t)(o0+rowA)*KTOT + koff;      // B chunks t -> rows 0..63
  const u16* bG1 = bG0 + (size_t)64*KTOT;                    // chunks 256+t -> rows 64..127
  u16* aL  = smem + tid*8;
  u16* bL0 = smem + 2048 + tid*8;
  u16* bL1 = smem + 4096 + tid*8;

  // xj-fusion per-thread constants (all rows of this block share one batch: 64 | SPB)
  const int bA = m0 / SPB;
  const int sA = (m0 - bA*SPB) + rowA;
  const int yA = sA / 56, xA = sA - yA*56;
  const u16* cmp = XJF ? (cminb + ((size_t)(bA*2+(yA&1))*56 + xA)*256 + koff) : nullptr;
  const u16* rmp = XJF ? (rminb + ((size_t)(bA*2+(xA&1))*56 + yA)*256 + koff) : nullptr;

  #pragma unroll
  for (int it = 0; it < NIT; ++it) {
    const int kt = it*32;
    short8 va, vb0, vb1;
    vb0 = *(const short8*)(bG0 + kt);
    vb1 = *(const short8*)(bG1 + kt);
    if (!XJF || kt < 256) {
      va = *(const short8*)(aG + kt);
    } else {
      short8 hv = *(const short8*)(aG + (kt - 256));
      short8 cv = *(const short8*)(cmp + (kt - 256));
      short8 rv = *(const short8*)(rmp + (kt - 256));
      #pragma unroll
      for (int j=0;j<8;j++){
        float hf = b2f((u16)hv[j]);
        float mn = fminf(b2f((u16)cv[j]), b2f((u16)rv[j]));
        va[j] = (short)f2b(fmaxf(0.0f, hf - mn));
      }
    }
    *(short8*)aL  = va;
    *(short8*)bL0 = vb0;
    *(short8*)bL1 = vb1;
    __syncthreads();
    short8 af[2], bfr[4];
    #pragma unroll
    for (int im=0;im<2;im++) af[im]  = *(const short8*)&smem[((wm*2+im)*64 + lane)*8];
    #pragma unroll
    for (int in=0;in<4;in++) bfr[in] = *(const short8*)&smem[2048 + ((wn*4+in)*64 + lane)*8];
    #pragma unroll
    for (int im=0;im<2;im++)
      #pragma unroll
      for (int in=0;in<4;in++)
        acc[im][in] = __builtin_amdgcn_mfma_f32_16x16x32_bf16(af[im], bfr[in], acc[im][in], 0, 0, 0);
    __syncthreads();
  }

  if (EPI == 1 || EPI == 2) {
    constexpr int OST = (EPI==1) ? 256 : 512;
    u16* tile = smem; // [64 m][128 o] = 16KB
    #pragma unroll
    for (int im=0;im<2;im++)
      #pragma unroll
      for (int in=0;in<4;in++){
        int ol = wn*64 + in*16 + l16;
        float sc = scale[o0+ol], bi = bias[o0+ol];
        #pragma unroll
        for (int r=0;r<4;r++){
          float v = acc[im][in][r]*sc + bi;
          if (EPI==2) v = gelu_f(v);
          tile[(wm*32+im*16+quad*4+r)*128 + ol] = f2b(v);
        }
      }
    __syncthreads();
    u16* op = (u16*)outp;
    #pragma unroll
    for (int p=0;p<4;p++){
      int chunk = p*256 + tid;
      int rr = chunk >> 4, off = (chunk & 15)*8;
      *(uint4*)&op[((size_t)(m0 + rr))*OST + o0 + off] = *(const uint4*)&tile[rr*128 + off];
    }
  } else {
    float* ftile = (float*)smem; // [64 o][68 m] padded, one 64-chan half at a time
    float* op = (float*)outp;
    const int b = m0 / SPB, s0 = m0 - b*SPB;
    #pragma unroll
    for (int h=0; h<2; h++){
      if (wn == h){
        #pragma unroll
        for (int im=0;im<2;im++)
          #pragma unroll
          for (int in=0;in<4;in++){
            int c64 = in*16 + l16;
            int og = o0 + h*64 + c64;
            float sc = scale[og], bi = bias[og];
            float4v v;
            #pragma unroll
            for (int r=0;r<4;r++) v[r] = acc[im][in][r]*sc + bi;
            *(float4v*)&ftile[c64*68 + wm*32 + im*16 + quad*4] = v;
          }
      }
      __syncthreads();
      #pragma unroll
      for (int p=0;p<4;p++){
        int chunk = p*256 + tid;
        int rr = chunk >> 4, off = (chunk & 15)*4;
        size_t g = ((size_t)(b*256 + o0 + h*64 + rr))*SPB + s0 + off;
        float4v v = *(const float4v*)&ftile[rr*68 + off];
        v.x += resid[g]; v.y += resid[g+1]; v.z += resid[g+2]; v.w += resid[g+3];
        *(float4v*)&op[g] = v;
      }
      __syncthreads();
    }
  }
}

extern "C" void kernel_launch(void* const* d_in, const int* in_sizes, int n_in,
                              void* d_out, int out_size, void* d_ws, size_t ws_size,
                              hipStream_t stream)
{
  const float* x  = (const float*)d_in[0];
  const float* w1 = (const float*)d_in[1];
  const float* b1 = (const float*)d_in[2];
  const float* g1 = (const float*)d_in[3];
  const float* be1= (const float*)d_in[4];
  const float* m1 = (const float*)d_in[5];
  const float* v1 = (const float*)d_in[6];
  const float* wg = (const float*)d_in[7];
  const float* bg = (const float*)d_in[8];
  const float* gg = (const float*)d_in[9];
  const float* beg= (const float*)d_in[10];
  const float* mg = (const float*)d_in[11];
  const float* vg = (const float*)d_in[12];
  const float* w2 = (const float*)d_in[13];
  const float* b2 = (const float*)d_in[14];
  const float* g2 = (const float*)d_in[15];
  const float* be2= (const float*)d_in[16];
  const float* m2 = (const float*)d_in[17];
  const float* v2 = (const float*)d_in[18];

  char* ws = (char*)d_ws;
  size_t off = 0;
  auto alloc = [&](size_t bytes){ void* p = ws + off; off += (bytes + 255) & ~(size_t)255; return p; };
  u16* xt    = (u16*)alloc((size_t)MTOT*256*2);   // x transposed, bf16
  u16* catt  = (u16*)alloc((size_t)MTOT*256*2);   // h only, [m][256] bf16
  u16* gt    = (u16*)alloc((size_t)MTOT*512*2);   // gelu output, [m][512] bf16
  u16* w1b   = (u16*)alloc((size_t)65536*2);
  u16* wgb   = (u16*)alloc((size_t)262144*2);
  u16* w2b   = (u16*)alloc((size_t)131072*2);
  float* cst = (float*)alloc((size_t)2048*4);
  u16* rmin  = (u16*)alloc((size_t)NB*2*56*256*2);
  u16* cmin  = (u16*)alloc((size_t)NB*2*56*256*2);

  hipLaunchKernelGGL(prep_k, dim3(512), dim3(512), 0, stream,
                     b1,g1,be1,m1,v1, bg,gg,beg,mg,vg, b2,g2,be2,m2,v2,
                     w1,wg,w2, w1b,wgb,w2b, cst);
  hipLaunchKernelGGL(transpose_x_k, dim3(98,8,8), dim3(32,8), 0, stream, x, xt);
  hipLaunchKernelGGL((gemm_k<256,256,1,false>), dim3(392,2), dim3(256), 0, stream,
                     xt, w1b, cst+0, cst+256, (void*)catt, (const float*)nullptr,
                     (const u16*)nullptr, (const u16*)nullptr);
  hipLaunchKernelGGL(minrc_k, dim3(NB*56,2), dim3(256), 0, stream, catt, rmin, cmin);
  hipLaunchKernelGGL((gemm_k<512,256,2,true>), dim3(392,4), dim3(256), 0, stream,
                     catt, wgb, cst+512, cst+1024, (void*)gt, (const float*)nullptr,
                     cmin, rmin);
  hipLaunchKernelGGL((gemm_k<512,512,3,false>), dim3(392,2), dim3(256), 0, stream,
                     gt, w2b, cst+1536, cst+1792, d_out, x,
                     (const u16*)nullptr, (const u16*)nullptr);
}